// Round 3
// baseline (363.820 us; speedup 1.0000x reference)
//
#include <hip/hip_runtime.h>

typedef _Float16 half8 __attribute__((ext_vector_type(8)));
typedef float f32x4 __attribute__((ext_vector_type(4)));

#define NRAYS 2048
#define SAMP 84
#define NPTS (NRAYS*SAMP)   // 172032
#define SEMSTR 52           // padded sem row stride (halves), 104B -> 8B aligned

// ---- half-element offsets inside the weight region (fragment-packed) ----
// layout per region: [frag F][kt][lane l][h 0..7] ; n = F*16 + (l&15), k = kt*32 + (l>>4)*8 + h
#define WT0_OFF   0         // 16 frags x KT2
#define WTH_OFF   16384     // 6 x (16 frags x KT8)
#define WTS_OFF   409600    // 16 frags x KT10
#define WTHD_OFF  491520    // 20 frags x KT8
#define WTR1_OFF  573440    // 8 frags x KT9
#define WTR2_OFF  610304    // 1 frag x KT4
#define WT_TOTAL  612352
#define NBIAS     2512

// ---- ws byte offsets ----
#define OFF_WT    ((size_t)0)
#define OFF_BIAS  ((size_t)1224704)                 // WT_TOTAL*2
#define OFF_Z     (OFF_BIAS + (size_t)NBIAS*4)
#define OFF_SCALE (OFF_Z + (size_t)NPTS*4)
#define OFF_SIGMA (OFF_SCALE + (size_t)NRAYS*4)
#define OFF_RGB   (OFF_SIGMA + (size_t)NPTS*4)
#define OFF_SEM   (OFF_RGB + (size_t)NPTS*12)

// ============================================================== prep
__global__ __launch_bounds__(256) void prep_kernel(
    const float* __restrict__ w_in,  const float* __restrict__ w_h,
    const float* __restrict__ w_skip,const float* __restrict__ w_sigma,
    const float* __restrict__ w_feat,const float* __restrict__ w_rgb1,
    const float* __restrict__ w_rgb2,const float* __restrict__ w_sem,
    const float* __restrict__ b_in,  const float* __restrict__ b_h,
    const float* __restrict__ b_skip,const float* __restrict__ b_sigma,
    const float* __restrict__ b_feat,const float* __restrict__ b_rgb1,
    const float* __restrict__ b_rgb2,const float* __restrict__ b_sem,
    _Float16* __restrict__ wt, float* __restrict__ bias)
{
  int idx = blockIdx.x*256 + threadIdx.x;
  if (idx < WT_TOTAL) {
    float v; int n, k, l, h, q;
    if (idx < WTH_OFF) {                 // L0: 16 frags, KT=2
      int r = idx; int F = r >> 10; int rem = r & 1023; int kt = rem >> 9; q = rem & 511;
      l = q >> 3; h = q & 7;
      n = F*16 + (l&15); k = kt*32 + (l>>4)*8 + h;
      v = (k < 63) ? w_in[k*256 + n] : 0.f;
    } else if (idx < WTS_OFF) {          // hidden: 6 x (16 frags x KT8)
      int r = idx - WTH_OFF; int i = r >> 16; int r2 = r & 65535;
      int F = r2 >> 12; int kt = (r2 >> 9) & 7; q = r2 & 511;
      l = q >> 3; h = q & 7;
      n = F*16 + (l&15); k = kt*32 + (l>>4)*8 + h;
      v = w_h[(i<<16) + (k<<8) + n];
    } else if (idx < WTHD_OFF) {         // skip: 16 frags x KT10
      int r = idx - WTS_OFF; int F = r / 5120; int rem = r % 5120; int kt = rem >> 9; q = rem & 511;
      l = q >> 3; h = q & 7;
      n = F*16 + (l&15); k = kt*32 + (l>>4)*8 + h;
      v = (k < 319) ? w_skip[k*256 + n] : 0.f;
    } else if (idx < WTR1_OFF) {         // head: 20 frags x KT8
      int r = idx - WTHD_OFF; int F = r >> 12; int kt = (r >> 9) & 7; q = r & 511;
      l = q >> 3; h = q & 7;
      n = F*16 + (l&15); k = kt*32 + (l>>4)*8 + h;
      v = (n < 256) ? w_feat[(k<<8) + n]
        : (n < 306) ? w_sem[k*50 + (n-256)]
        : (n == 306)? w_sigma[k] : 0.f;
    } else if (idx < WTR2_OFF) {         // rgb1: 8 frags x KT9
      int r = idx - WTR1_OFF; int F = r / 4608; int rem = r % 4608; int kt = rem >> 9; q = rem & 511;
      l = q >> 3; h = q & 7;
      n = F*16 + (l&15); k = kt*32 + (l>>4)*8 + h;
      v = (k < 283) ? w_rgb1[k*128 + n] : 0.f;
    } else {                             // rgb2: 1 frag x KT4
      int r = idx - WTR2_OFF; int kt = r >> 9; q = r & 511;
      l = q >> 3; h = q & 7;
      n = (l&15); k = kt*32 + (l>>4)*8 + h;
      v = (n < 3) ? w_rgb2[k*3 + n] : 0.f;
    }
    wt[idx] = (_Float16)v;
  } else if (idx < WT_TOTAL + NBIAS) {
    int j = idx - WT_TOTAL; float v;
    if (j < 2048) {
      int i = j >> 8, c = j & 255;
      v = (i==0) ? b_in[c] : (i<4) ? b_h[(i-1)*256+c]
        : (i==4) ? b_skip[c] : b_h[(i-2)*256+c];
    } else if (j < 2368) {
      int c = j - 2048;
      v = (c<256) ? b_feat[c] : (c<306) ? b_sem[c-256]
        : (c==306) ? b_sigma[0] : 0.f;
    } else if (j < 2496) v = b_rgb1[j-2368];
    else { int c = j-2496; v = (c<3) ? b_rgb2[c] : 0.f; }
    bias[j] = v;
  }
}

// ============================================================== sampling
__global__ __launch_bounds__(256) void sample_kernel(
    const float* __restrict__ rays, const float* __restrict__ inter,
    const float* __restrict__ noise, float* __restrict__ zbuf,
    float* __restrict__ scaleb)
{
  __shared__ float sv[240], ss[240], z2[84];
  const int ray = blockIdx.x, t = threadIdx.x;
  const float* bx = inter + (size_t)ray*40;
  if (t < 240) {
    int b = t/24, j = t%24;
    float nr = bx[b*4], fr = bx[b*4+1];
    float tj = (j==23) ? 1.f : (float)j * (1.f/23.f);
    sv[t] = nr + (fr-nr)*tj;
  }
  __syncthreads();
  if (t < 240) {
    float v = sv[t]; int r = 0;
    for (int i = 0; i < 240; ++i) { float vi = sv[i]; r += (vi < v) || (vi == v && i < t); }
    ss[r] = v;
  }
  __syncthreads();
  if (t < 64) {
    float z;
    if (t == 63) z = ss[239];
    else { int num = t*239; int k = num/63; float f = (float)(num - k*63)*(1.f/63.f);
           z = ss[k] + f*(ss[k+1]-ss[k]); }
    z2[t] = z;
  } else if (t < 84) {
    int b = t - 64;
    z2[t] = (b < 10) ? (bx[b*4] - 1e-5f) : (bx[(b-10)*4+1] + 1e-5f);
  }
  __syncthreads();
  if (t < 84) { float z = z2[t]; if (z < 0.f) z = 200.f + 20.f*noise[(size_t)ray*84 + t]; z2[t] = z; }
  __syncthreads();
  if (t < 84) {
    float v = z2[t]; int r = 0;
    for (int i = 0; i < 84; ++i) { float vi = z2[i]; r += (vi < v) || (vi == v && i < t); }
    zbuf[(size_t)ray*84 + r] = v;
  }
  if (t == 0) {
    float dx = rays[ray*6+3], dy = rays[ray*6+4], dz = rays[ray*6+5];
    scaleb[ray] = sqrtf(dx*dx + dy*dy + dz*dz);
  }
}

// ============================================================== MLP
// 128 points/block, 1024 threads (16 waves = 4n x 4m).
// LDS: bufA (128x256 f16, 64KB) @0, bufB @65536, bufX (128x64 f16, 16KB) @131072.
#define LDS_A 0u
#define LDS_B 65536u
#define LDS_X 131072u
#define LDS_TOTAL 147456

__device__ __forceinline__ uint32_t laddr(uint32_t base, int m, int k) {
  return base + (uint32_t)(m*512) + (uint32_t)((((k>>3)^(m&7))<<4) + ((k&7)<<1));
}
__device__ __forceinline__ uint32_t laddrX(int m, int k) {
  return LDS_X + (uint32_t)(m*128) + (uint32_t)(((((k>>3)&7)^(m&7))<<4) + ((k&7)<<1));
}
struct __attribute__((aligned(8))) H4 { _Float16 h[4]; };

__device__ __forceinline__ float xenc_val(int j, float x0, float x1, float x2) {
  if (j >= 63) return 0.f;
  if (j < 3) return j==0?x0:(j==1?x1:x2);
  int q = j-3, lf = q/6, r = q%6, ci = r%3;
  float xc = (ci==0)?x0:((ci==1)?x1:x2);
  float arg = xc * (float)(1<<lf);
  return (r<3) ? sinf(arg) : cosf(arg);
}
__device__ __forceinline__ float denc_val(int c, float u0, float u1, float u2) {
  if (c >= 27) return 0.f;
  if (c < 3) return c==0?u0:(c==1?u1:u2);
  int q = c-3, lf = q/6, r = q%6, ci = r%3;
  float uc = (ci==0)?u0:((ci==1)?u1:u2);
  float arg = uc * (float)(1<<lf);
  return (r<3) ? sinf(arg) : cosf(arg);
}

// 16 waves: wn = w>>2 (0..3) over cols, wm = w&3 (0..3) over rows.
// Per wave: rows wm*32+[0,32) (MF=2), cols wn*(NF*16)+[0,NF*16).
// XSTART: 0 => whole input from bufX; 100000 => all from inb; else k>=XSTART reads bufX col k-XSTART.
template<int KT, int NF, int MF, int MODE, bool RELU, int XSTART>
__device__ __forceinline__ void gemm(uint8_t* smem, uint32_t inb, uint32_t outb,
    const _Float16* __restrict__ WT, const float* __restrict__ bias,
    int p0, float* __restrict__ sigmaws, _Float16* __restrict__ semws)
{
  const int t = threadIdx.x;
  const int l = t & 63, w = t >> 6;
  const int lr = l & 15, lg = l >> 4;
  const int wn = w >> 2, wm = w & 3;
  const int m0 = wm*(MF*16);
  constexpr int DEPTH = (NF > 4) ? 2 : 3;   // weight prefetch depth (VGPR budget)
  f32x4 acc[NF][MF];
#pragma unroll
  for (int i = 0; i < NF; ++i)
#pragma unroll
    for (int j = 0; j < MF; ++j) acc[i][j] = (f32x4){0.f,0.f,0.f,0.f};
  const _Float16* wb = WT + (size_t)(wn*NF*KT)*512 + (size_t)l*8;
  half8 av[DEPTH][NF];
  half8 bv[2][MF];
  // prologue: weights kt=0..DEPTH-1, activations kt=0
#pragma unroll
  for (int d = 0; d < DEPTH; ++d) {
    if (d < KT) {
#pragma unroll
      for (int nf = 0; nf < NF; ++nf)
        av[d][nf] = *(const half8*)(wb + (size_t)(nf*KT + d)*512);
    }
  }
#pragma unroll
  for (int mf = 0; mf < MF; ++mf) {
    const int row = m0 + mf*16 + lr;
    const int kk = lg*8;
    uint32_t a = (XSTART == 0) ? laddrX(row, kk)
               : (0 >= XSTART) ? laddrX(row, kk - XSTART) : laddr(inb, row, kk);
    bv[0][mf] = *(const half8*)(smem + a);
  }
#pragma unroll
  for (int kt = 0; kt < KT; ++kt) {
    // prefetch next B (1 ahead)
    if (kt + 1 < KT) {
      const int kn = (kt+1)*32 + lg*8;
#pragma unroll
      for (int mf = 0; mf < MF; ++mf) {
        const int row = m0 + mf*16 + lr;
        uint32_t a;
        if (XSTART == 0)                 a = laddrX(row, kn);
        else if ((kt+1)*32 >= XSTART)    a = laddrX(row, kn - XSTART);
        else                             a = laddr(inb, row, kn);
        bv[(kt+1)&1][mf] = *(const half8*)(smem + a);
      }
    }
    // MFMA on current
#pragma unroll
    for (int nf = 0; nf < NF; ++nf)
#pragma unroll
      for (int mf = 0; mf < MF; ++mf)
        acc[nf][mf] = __builtin_amdgcn_mfma_f32_16x16x32_f16(av[kt%DEPTH][nf], bv[kt&1][mf], acc[nf][mf], 0, 0, 0);
    // prefetch weights DEPTH ahead (slot just freed)
    if (kt + DEPTH < KT) {
#pragma unroll
      for (int nf = 0; nf < NF; ++nf)
        av[(kt+DEPTH)%DEPTH][nf] = *(const half8*)(wb + (size_t)(nf*KT + kt + DEPTH)*512);
    }
  }
#pragma unroll
  for (int nf = 0; nf < NF; ++nf) {
    const int n0 = wn*(NF*16) + nf*16;
    const int nb = n0 + lg*4;
    const f32x4 bvv = *(const f32x4*)(bias + nb);
#pragma unroll
    for (int mf = 0; mf < MF; ++mf) {
      const int m = m0 + mf*16 + lr;
      f32x4 v = acc[nf][mf] + bvv;
      if (MODE == 0 || n0 < 256) {
        H4 hh;
#pragma unroll
        for (int r = 0; r < 4; ++r) { float x = v[r]; if (RELU) x = fmaxf(x, 0.f); hh.h[r] = (_Float16)x; }
        *(H4*)(smem + laddr(outb, m, nb)) = hh;
      } else {
        const int pp = p0 + m;
        const int c = nb - 256;
        if (c <= 44) {                       // 4 sem cols, 8B aligned store
          H4 hh;
#pragma unroll
          for (int r = 0; r < 4; ++r) hh.h[r] = (_Float16)v[r];
          *(H4*)(semws + (size_t)pp*SEMSTR + c) = hh;
        } else if (c == 48) {                // cols 48,49 + sigma (n=306)
          semws[(size_t)pp*SEMSTR + 48] = (_Float16)v[0];
          semws[(size_t)pp*SEMSTR + 49] = (_Float16)v[1];
          sigmaws[pp] = v[2];
        }
      }
    }
  }
}

__device__ __forceinline__ void gemm_rgb2(uint8_t* smem, uint32_t inb,
    const _Float16* __restrict__ WT, const float* __restrict__ bias,
    int p0, float* __restrict__ rgbws)
{
  const int t = threadIdx.x;
  const int l = t & 63, w = t >> 6;
  if (w >= 8) return;
  const int lr = l & 15, lg = l >> 4;
  const int m0 = w*16;
  f32x4 acc = (f32x4){0.f,0.f,0.f,0.f};
#pragma unroll
  for (int kt = 0; kt < 4; ++kt) {
    const int kk = kt*32 + lg*8;
    half8 a = *(const half8*)(WT + (size_t)kt*512 + (size_t)l*8);
    half8 b = *(const half8*)(smem + laddr(inb, m0 + lr, kk));
    acc = __builtin_amdgcn_mfma_f32_16x16x32_f16(a, b, acc, 0, 0, 0);
  }
  const int pp = p0 + m0 + lr;
#pragma unroll
  for (int r = 0; r < 4; ++r) {
    const int n = lg*4 + r;
    if (n < 3) rgbws[(size_t)pp*3 + n] = (float)acc[r] + bias[n];
  }
}

__global__ __launch_bounds__(1024,4) void mlp_kernel(
    const float* __restrict__ rays, const float* __restrict__ zbuf,
    const float* __restrict__ scaleb, const _Float16* __restrict__ wt,
    const float* __restrict__ bias, float* __restrict__ sigmaws,
    float* __restrict__ rgbws, _Float16* __restrict__ semws)
{
  extern __shared__ uint8_t smem[];
  const int p0 = blockIdx.x*128;
  const int t = threadIdx.x;
  const int m = t & 127, g = t >> 7;
  const int p = p0 + m;
  const int ray = p / SAMP;
  const float sc = scaleb[ray];
  const float z  = zbuf[p];
  const float ox = rays[ray*6+0], oy = rays[ray*6+1], oz = rays[ray*6+2];
  const float dx = rays[ray*6+3], dy = rays[ray*6+4], dz = rays[ray*6+5];
  const float x0 = (ox + dx*z/sc)/200.f;
  const float x1 = (oy + dy*z/sc)/200.f;
  const float x2 = (oz + dz*z/sc)/200.f;
  const float u0 = dx/sc, u1 = dy/sc, u2 = dz/sc;
  // x_enc -> bufX (each thread: row m, cols g*8..g*8+7, one 16B write)
  {
    union { _Float16 hv[8]; half8 v; } u8;
    const int j0 = g*8;
#pragma unroll
    for (int jj = 0; jj < 8; ++jj) u8.hv[jj] = (_Float16)xenc_val(j0+jj, x0, x1, x2);
    *(half8*)(smem + laddrX(m, j0)) = u8.v;
  }
  __syncthreads();
  gemm<2 ,4,2,0,true ,0     >(smem, LDS_X, LDS_A, wt+WT0_OFF,          bias+0,    p0, sigmaws, semws); __syncthreads();
  gemm<8 ,4,2,0,true ,100000>(smem, LDS_A, LDS_B, wt+WTH_OFF+0*65536,  bias+256,  p0, sigmaws, semws); __syncthreads();
  gemm<8 ,4,2,0,true ,100000>(smem, LDS_B, LDS_A, wt+WTH_OFF+1*65536,  bias+512,  p0, sigmaws, semws); __syncthreads();
  gemm<8 ,4,2,0,true ,100000>(smem, LDS_A, LDS_B, wt+WTH_OFF+2*65536,  bias+768,  p0, sigmaws, semws); __syncthreads();
  gemm<10,4,2,0,true ,256   >(smem, LDS_B, LDS_A, wt+WTS_OFF,          bias+1024, p0, sigmaws, semws); __syncthreads();
  // overwrite bufX cols 0..31 with d_enc (x_enc dead after skip layer)
  {
    union { _Float16 hv[4]; H4 v; } u4;
    const int c0 = g*4;
#pragma unroll
    for (int cc = 0; cc < 4; ++cc) u4.hv[cc] = (_Float16)denc_val(c0+cc, u0, u1, u2);
    *(H4*)(smem + laddrX(m, c0)) = u4.v;
  }
  gemm<8 ,4,2,0,true ,100000>(smem, LDS_A, LDS_B, wt+WTH_OFF+3*65536,  bias+1280, p0, sigmaws, semws); __syncthreads();
  gemm<8 ,4,2,0,true ,100000>(smem, LDS_B, LDS_A, wt+WTH_OFF+4*65536,  bias+1536, p0, sigmaws, semws); __syncthreads();
  gemm<8 ,4,2,0,true ,100000>(smem, LDS_A, LDS_B, wt+WTH_OFF+5*65536,  bias+1792, p0, sigmaws, semws); __syncthreads();
  gemm<8 ,5,2,1,false,100000>(smem, LDS_B, LDS_A, wt+WTHD_OFF,         bias+2048, p0, sigmaws, semws); __syncthreads();
  gemm<9 ,2,2,0,true ,256   >(smem, LDS_A, LDS_B, wt+WTR1_OFF,         bias+2368, p0, sigmaws, semws); __syncthreads();
  gemm_rgb2(smem, LDS_B, wt+WTR2_OFF, bias+2496, p0, rgbws);
}

// ============================================================== compositing
__global__ __launch_bounds__(128) void comp_kernel(
    const float* __restrict__ inter, const float* __restrict__ zbuf,
    const float* __restrict__ scaleb, const float* __restrict__ sigmaws,
    const float* __restrict__ rgbws, const _Float16* __restrict__ semws,
    float* __restrict__ out)
{
  __shared__ float zt[84], alpha[84], wgt[84];
  const int ray = blockIdx.x, t = threadIdx.x;
  const float sc = scaleb[ray];
  const float* bx = inter + (size_t)ray*40;
  if (t < 84) zt[t] = zbuf[(size_t)ray*84 + t] / sc;
  __syncthreads();
  if (t < 84) {
    const float z = zbuf[(size_t)ray*84 + t];
    bool inside = false, bound = false;
    for (int b = 0; b < 10; ++b) {
      const float nr = bx[b*4], fr = bx[b*4+1];
      inside = inside || (z > nr && z < fr);
      const float d1 = z - fr, d2 = nr - z;
      bound = bound || (d1 > 0.f && d1 < 1e-3f) || (d2 > 0.f && d2 < 1e-3f);
    }
    float sg = sigmaws[(size_t)ray*84 + t];
    const bool bbox = (z < 200.f) && !inside;
    if (bbox || bound) sg = 0.f;
    sg = fmaxf(sg, 0.f);
    const float dist = (t < 83) ? (zt[t+1] - zt[t])*sc : 1e10f*sc;
    alpha[t] = 1.f - expf(-sg*dist);
  }
  __syncthreads();
  if (t == 0) {
    float T = 1.f;
    for (int s = 0; s < 84; ++s) { wgt[s] = alpha[s]*T; T *= (1.f - alpha[s] + 1e-10f); }
  }
  __syncthreads();
  if (t < 55) {
    float a = 0.f;
    const size_t base = (size_t)ray*84;
    if (t < 50) {
      for (int s = 0; s < 84; ++s) a += wgt[s]*(float)semws[(base+s)*SEMSTR + t];
      out[(size_t)ray*55 + 5 + t] = a;
    } else if (t < 53) {
      const int c = t - 50;
      for (int s = 0; s < 84; ++s) { const float r = rgbws[(base+s)*3 + c]; a += wgt[s]/(1.f + expf(-r)); }
      out[(size_t)ray*55 + c] = a;
    } else if (t == 53) {
      for (int s = 0; s < 84; ++s) a += wgt[s]*zt[s];
      out[(size_t)ray*55 + 3] = a;
    } else {
      for (int s = 0; s < 84; ++s) a += wgt[s];
      out[(size_t)ray*55 + 4] = a;
    }
  }
}

// ============================================================== launch
extern "C" void kernel_launch(void* const* d_in, const int* in_sizes, int n_in,
                              void* d_out, int out_size, void* d_ws, size_t ws_size,
                              hipStream_t stream) {
  const float* rays   = (const float*)d_in[0];
  const float* inter  = (const float*)d_in[1];
  const float* noise  = (const float*)d_in[2];
  const float* w_in   = (const float*)d_in[3];
  const float* b_in   = (const float*)d_in[4];
  const float* w_h    = (const float*)d_in[5];
  const float* b_h    = (const float*)d_in[6];
  const float* w_skip = (const float*)d_in[7];
  const float* b_skip = (const float*)d_in[8];
  const float* w_sig  = (const float*)d_in[9];
  const float* b_sig  = (const float*)d_in[10];
  const float* w_feat = (const float*)d_in[11];
  const float* b_feat = (const float*)d_in[12];
  const float* w_rgb1 = (const float*)d_in[13];
  const float* b_rgb1 = (const float*)d_in[14];
  const float* w_rgb2 = (const float*)d_in[15];
  const float* b_rgb2 = (const float*)d_in[16];
  const float* w_sem  = (const float*)d_in[17];
  const float* b_sem  = (const float*)d_in[18];

  uint8_t* ws = (uint8_t*)d_ws;
  _Float16* wt    = (_Float16*)(ws + OFF_WT);
  float* bias     = (float*)(ws + OFF_BIAS);
  float* zbuf     = (float*)(ws + OFF_Z);
  float* scaleb   = (float*)(ws + OFF_SCALE);
  float* sigmaws  = (float*)(ws + OFF_SIGMA);
  float* rgbws    = (float*)(ws + OFF_RGB);
  _Float16* semws = (_Float16*)(ws + OFF_SEM);

  prep_kernel<<<dim3((WT_TOTAL + NBIAS + 255)/256), dim3(256), 0, stream>>>(
      w_in, w_h, w_skip, w_sig, w_feat, w_rgb1, w_rgb2, w_sem,
      b_in, b_h, b_skip, b_sig, b_feat, b_rgb1, b_rgb2, b_sem, wt, bias);
  sample_kernel<<<dim3(NRAYS), dim3(256), 0, stream>>>(rays, inter, noise, zbuf, scaleb);
  mlp_kernel<<<dim3(NPTS/128), dim3(1024), LDS_TOTAL, stream>>>(
      rays, zbuf, scaleb, wt, bias, sigmaws, rgbws, semws);
  comp_kernel<<<dim3(NRAYS), dim3(128), 0, stream>>>(
      inter, zbuf, scaleb, sigmaws, rgbws, semws, (float*)d_out);
}

// Round 4
// 321.999 us; speedup vs baseline: 1.1299x; 1.1299x over previous
//
#include <hip/hip_runtime.h>

typedef _Float16 half8 __attribute__((ext_vector_type(8)));
typedef float f32x4 __attribute__((ext_vector_type(4)));

#define NRAYS 2048
#define SAMP 84
#define NPTS (NRAYS*SAMP)   // 172032
#define SEMSTR 52           // padded sem row stride (halves)

// ---- half-element offsets inside the weight region (fragment-packed) ----
// layout per region: [frag F][kt][lane l][h 0..7] ; n = F*16 + (l&15), k = kt*32 + (l>>4)*8 + h
#define WT0_OFF   0         // 16 frags x KT2
#define WTH_OFF   16384     // 6 x (16 frags x KT8)
#define WTS_OFF   409600    // 16 frags x KT10
#define WTHD_OFF  491520    // 20 frags x KT8
#define WTR1_OFF  573440    // 8 frags x KT9
#define WTR2_OFF  610304    // 1 frag x KT4
#define WT_TOTAL  612352
#define NBIAS     2512

// ---- ws byte offsets ----
#define OFF_WT    ((size_t)0)
#define OFF_BIAS  ((size_t)1224704)                 // WT_TOTAL*2
#define OFF_Z     (OFF_BIAS + (size_t)NBIAS*4)
#define OFF_SCALE (OFF_Z + (size_t)NPTS*4)
#define OFF_SIGMA (OFF_SCALE + (size_t)NRAYS*4)
#define OFF_RGB   (OFF_SIGMA + (size_t)NPTS*4)
#define OFF_SEM   (OFF_RGB + (size_t)NPTS*12)

// ============================================================== prep
__global__ __launch_bounds__(256) void prep_kernel(
    const float* __restrict__ w_in,  const float* __restrict__ w_h,
    const float* __restrict__ w_skip,const float* __restrict__ w_sigma,
    const float* __restrict__ w_feat,const float* __restrict__ w_rgb1,
    const float* __restrict__ w_rgb2,const float* __restrict__ w_sem,
    const float* __restrict__ b_in,  const float* __restrict__ b_h,
    const float* __restrict__ b_skip,const float* __restrict__ b_sigma,
    const float* __restrict__ b_feat,const float* __restrict__ b_rgb1,
    const float* __restrict__ b_rgb2,const float* __restrict__ b_sem,
    _Float16* __restrict__ wt, float* __restrict__ bias)
{
  int idx = blockIdx.x*256 + threadIdx.x;
  if (idx < WT_TOTAL) {
    float v; int n, k, l, h, q;
    if (idx < WTH_OFF) {                 // L0: 16 frags, KT=2
      int r = idx; int F = r >> 10; int rem = r & 1023; int kt = rem >> 9; q = rem & 511;
      l = q >> 3; h = q & 7;
      n = F*16 + (l&15); k = kt*32 + (l>>4)*8 + h;
      v = (k < 63) ? w_in[k*256 + n] : 0.f;
    } else if (idx < WTS_OFF) {          // hidden: 6 x (16 frags x KT8)
      int r = idx - WTH_OFF; int i = r >> 16; int r2 = r & 65535;
      int F = r2 >> 12; int kt = (r2 >> 9) & 7; q = r2 & 511;
      l = q >> 3; h = q & 7;
      n = F*16 + (l&15); k = kt*32 + (l>>4)*8 + h;
      v = w_h[(i<<16) + (k<<8) + n];
    } else if (idx < WTHD_OFF) {         // skip: 16 frags x KT10
      int r = idx - WTS_OFF; int F = r / 5120; int rem = r % 5120; int kt = rem >> 9; q = rem & 511;
      l = q >> 3; h = q & 7;
      n = F*16 + (l&15); k = kt*32 + (l>>4)*8 + h;
      v = (k < 319) ? w_skip[k*256 + n] : 0.f;
    } else if (idx < WTR1_OFF) {         // head: 20 frags x KT8
      int r = idx - WTHD_OFF; int F = r >> 12; int kt = (r >> 9) & 7; q = r & 511;
      l = q >> 3; h = q & 7;
      n = F*16 + (l&15); k = kt*32 + (l>>4)*8 + h;
      v = (n < 256) ? w_feat[(k<<8) + n]
        : (n < 306) ? w_sem[k*50 + (n-256)]
        : (n == 306)? w_sigma[k] : 0.f;
    } else if (idx < WTR2_OFF) {         // rgb1: 8 frags x KT9
      int r = idx - WTR1_OFF; int F = r / 4608; int rem = r % 4608; int kt = rem >> 9; q = rem & 511;
      l = q >> 3; h = q & 7;
      n = F*16 + (l&15); k = kt*32 + (l>>4)*8 + h;
      v = (k < 283) ? w_rgb1[k*128 + n] : 0.f;
    } else {                             // rgb2: 1 frag x KT4
      int r = idx - WTR2_OFF; int kt = r >> 9; q = r & 511;
      l = q >> 3; h = q & 7;
      n = (l&15); k = kt*32 + (l>>4)*8 + h;
      v = (n < 3) ? w_rgb2[k*3 + n] : 0.f;
    }
    wt[idx] = (_Float16)v;
  } else if (idx < WT_TOTAL + NBIAS) {
    int j = idx - WT_TOTAL; float v;
    if (j < 2048) {
      int i = j >> 8, c = j & 255;
      v = (i==0) ? b_in[c] : (i<4) ? b_h[(i-1)*256+c]
        : (i==4) ? b_skip[c] : b_h[(i-2)*256+c];
    } else if (j < 2368) {
      int c = j - 2048;
      v = (c<256) ? b_feat[c] : (c<306) ? b_sem[c-256]
        : (c==306) ? b_sigma[0] : 0.f;
    } else if (j < 2496) v = b_rgb1[j-2368];
    else { int c = j-2496; v = (c<3) ? b_rgb2[c] : 0.f; }
    bias[j] = v;
  }
}

// ============================================================== sampling
__global__ __launch_bounds__(256) void sample_kernel(
    const float* __restrict__ rays, const float* __restrict__ inter,
    const float* __restrict__ noise, float* __restrict__ zbuf,
    float* __restrict__ scaleb)
{
  __shared__ float sv[240], ss[240], z2[84];
  const int ray = blockIdx.x, t = threadIdx.x;
  const float* bx = inter + (size_t)ray*40;
  if (t < 240) {
    int b = t/24, j = t%24;
    float nr = bx[b*4], fr = bx[b*4+1];
    float tj = (j==23) ? 1.f : (float)j * (1.f/23.f);
    sv[t] = nr + (fr-nr)*tj;
  }
  __syncthreads();
  if (t < 240) {
    float v = sv[t]; int r = 0;
    for (int i = 0; i < 240; ++i) { float vi = sv[i]; r += (vi < v) || (vi == v && i < t); }
    ss[r] = v;
  }
  __syncthreads();
  if (t < 64) {
    float z;
    if (t == 63) z = ss[239];
    else { int num = t*239; int k = num/63; float f = (float)(num - k*63)*(1.f/63.f);
           z = ss[k] + f*(ss[k+1]-ss[k]); }
    z2[t] = z;
  } else if (t < 84) {
    int b = t - 64;
    z2[t] = (b < 10) ? (bx[b*4] - 1e-5f) : (bx[(b-10)*4+1] + 1e-5f);
  }
  __syncthreads();
  if (t < 84) { float z = z2[t]; if (z < 0.f) z = 200.f + 20.f*noise[(size_t)ray*84 + t]; z2[t] = z; }
  __syncthreads();
  if (t < 84) {
    float v = z2[t]; int r = 0;
    for (int i = 0; i < 84; ++i) { float vi = z2[i]; r += (vi < v) || (vi == v && i < t); }
    zbuf[(size_t)ray*84 + r] = v;
  }
  if (t == 0) {
    float dx = rays[ray*6+3], dy = rays[ray*6+4], dz = rays[ray*6+5];
    scaleb[ray] = sqrtf(dx*dx + dy*dy + dz*dz);
  }
}

// ============================================================== MLP
// 64 points/block, 256 threads (4 waves = 2n x 2m). Per wave: 32 rows x 128 cols.
// LDS: bufA (64x256 f16, 32KB) @0, bufB @32768, bufX (64x64 f16, 8KB) @65536. 72KB -> 2 blocks/CU.
#define LDS_A 0u
#define LDS_B 32768u
#define LDS_X 65536u
#define LDS_TOTAL 73728

__device__ __forceinline__ uint32_t laddr(uint32_t base, int m, int k) {
  return base + (uint32_t)(m*512) + (uint32_t)((((k>>3)^(m&7))<<4) + ((k&7)<<1));
}
__device__ __forceinline__ uint32_t laddrX(int m, int k) {
  return LDS_X + (uint32_t)(m*128) + (uint32_t)(((((k>>3)&7)^(m&7))<<4) + ((k&7)<<1));
}
struct __attribute__((aligned(8))) H4 { _Float16 h[4]; };

__device__ __forceinline__ float xenc_val(int j, float x0, float x1, float x2) {
  if (j >= 63) return 0.f;
  if (j < 3) return j==0?x0:(j==1?x1:x2);
  int q = j-3, lf = q/6, r = q%6, ci = r%3;
  float xc = (ci==0)?x0:((ci==1)?x1:x2);
  float arg = xc * (float)(1<<lf);
  return (r<3) ? sinf(arg) : cosf(arg);
}
__device__ __forceinline__ float denc_val(int c, float u0, float u1, float u2) {
  if (c >= 27) return 0.f;
  if (c < 3) return c==0?u0:(c==1?u1:u2);
  int q = c-3, lf = q/6, r = q%6, ci = r%3;
  float uc = (ci==0)?u0:((ci==1)?u1:u2);
  float arg = uc * (float)(1<<lf);
  return (r<3) ? sinf(arg) : cosf(arg);
}

// 4 waves: wn = w>>1 (0..1) over col-halves, wm = w&1 (0..1) over row-halves.
// Per wave: rows wm*32+[0,32) (MF=2), cols wn*(NF*16)+[0,NF*16).
// XSTART: 0 => input entirely bufX; 100000 => entirely inb; else k>=XSTART reads bufX col k-XSTART.
// MODE 0: write smem outb (opt RELU). MODE 1: head tail -> sem/sigma, col base wn*NF*16.
template<int KT, int NF, int MF, int MODE, bool RELU, int XSTART>
__device__ __forceinline__ void gemm(uint8_t* smem, uint32_t inb, uint32_t outb,
    const _Float16* __restrict__ WT, int fbase, const float* __restrict__ biasptr,
    int p0, float* __restrict__ sigmaws, _Float16* __restrict__ semws)
{
  const int t = threadIdx.x;
  const int l = t & 63, w = t >> 6;
  const int lr = l & 15, lg = l >> 4;
  const int wn = w >> 1, wm = w & 1;
  const int m0 = wm*(MF*16);
  constexpr int DW = (KT < 3) ? KT : 3;   // weight prefetch depth
  f32x4 acc[NF][MF];
#pragma unroll
  for (int i = 0; i < NF; ++i)
#pragma unroll
    for (int j = 0; j < MF; ++j) acc[i][j] = (f32x4){0.f,0.f,0.f,0.f};
  const _Float16* wb = WT + (size_t)((fbase + wn*NF)*KT)*512 + (size_t)l*8;
  half8 av[DW][NF];
  half8 bv[2][MF];
  // B-operand LDS address for k-tile kt
  auto baddr = [&](int row, int kt)->uint32_t {
    const int kk = kt*32 + lg*8;
    if (XSTART == 0) return laddrX(row, kk);
    if (XSTART < 100000 && kt*32 >= XSTART) return laddrX(row, kk - XSTART);
    return laddr(inb, row, kk);
  };
  // prologue: weights kt=0..DW-1, activations kt=0
#pragma unroll
  for (int d = 0; d < DW; ++d)
#pragma unroll
    for (int nf = 0; nf < NF; ++nf)
      av[d][nf] = *(const half8*)(wb + (size_t)(nf*KT + d)*512);
#pragma unroll
  for (int mf = 0; mf < MF; ++mf)
    bv[0][mf] = *(const half8*)(smem + baddr(m0 + mf*16 + lr, 0));
#pragma unroll
  for (int kt = 0; kt < KT; ++kt) {
    // prefetch next B tile (ds)
    if (kt + 1 < KT) {
#pragma unroll
      for (int mf = 0; mf < MF; ++mf)
        bv[(kt+1)&1][mf] = *(const half8*)(smem + baddr(m0 + mf*16 + lr, kt+1));
    }
    __builtin_amdgcn_sched_barrier(0);
#pragma unroll
    for (int nf = 0; nf < NF; ++nf)
#pragma unroll
      for (int mf = 0; mf < MF; ++mf)
        acc[nf][mf] = __builtin_amdgcn_mfma_f32_16x16x32_f16(av[kt%DW][nf], bv[kt&1][mf], acc[nf][mf], 0, 0, 0);
    __builtin_amdgcn_sched_barrier(0);
    // refill weight slot just consumed (DW-1 iterations ahead of use)
    if (kt + DW < KT) {
#pragma unroll
      for (int nf = 0; nf < NF; ++nf)
        av[kt%DW][nf] = *(const half8*)(wb + (size_t)(nf*KT + kt + DW)*512);
    }
  }
#pragma unroll
  for (int nf = 0; nf < NF; ++nf) {
    if (MODE == 0) {
      const int n0 = wn*(NF*16) + nf*16;
      const int nb = n0 + lg*4;
      const f32x4 bvv = *(const f32x4*)(biasptr + nb);
#pragma unroll
      for (int mf = 0; mf < MF; ++mf) {
        const int m = m0 + mf*16 + lr;
        f32x4 v = acc[nf][mf] + bvv;
        H4 hh;
#pragma unroll
        for (int r = 0; r < 4; ++r) { float x = v[r]; if (RELU) x = fmaxf(x, 0.f); hh.h[r] = (_Float16)x; }
        *(H4*)(smem + laddr(outb, m, nb)) = hh;
      }
    } else {
      const int cb = wn*(NF*16) + nf*16 + lg*4;   // col offset within head tail (0..63)
      const f32x4 bvv = *(const f32x4*)(biasptr + cb);
#pragma unroll
      for (int mf = 0; mf < MF; ++mf) {
        const int m = m0 + mf*16 + lr;
        const int pp = p0 + m;
        f32x4 v = acc[nf][mf] + bvv;
        if (cb <= 44) {                       // 4 sem cols, 8B aligned store
          H4 hh;
#pragma unroll
          for (int r = 0; r < 4; ++r) hh.h[r] = (_Float16)v[r];
          *(H4*)(semws + (size_t)pp*SEMSTR + cb) = hh;
        } else if (cb == 48) {                // sem 48,49 + sigma (c=50)
          semws[(size_t)pp*SEMSTR + 48] = (_Float16)v[0];
          semws[(size_t)pp*SEMSTR + 49] = (_Float16)v[1];
          sigmaws[pp] = v[2];
        }
      }
    }
  }
}

__device__ __forceinline__ void gemm_rgb2(uint8_t* smem, uint32_t inb,
    const _Float16* __restrict__ WT, const float* __restrict__ bias,
    int p0, float* __restrict__ rgbws)
{
  const int t = threadIdx.x;
  const int l = t & 63, w = t >> 6;
  const int lr = l & 15, lg = l >> 4;
  const int m0 = w*16;
  f32x4 acc = (f32x4){0.f,0.f,0.f,0.f};
#pragma unroll
  for (int kt = 0; kt < 4; ++kt) {
    const int kk = kt*32 + lg*8;
    half8 a = *(const half8*)(WT + (size_t)kt*512 + (size_t)l*8);
    half8 b = *(const half8*)(smem + laddr(inb, m0 + lr, kk));
    acc = __builtin_amdgcn_mfma_f32_16x16x32_f16(a, b, acc, 0, 0, 0);
  }
  const int pp = p0 + m0 + lr;
#pragma unroll
  for (int r = 0; r < 4; ++r) {
    const int n = lg*4 + r;
    if (n < 3) rgbws[(size_t)pp*3 + n] = (float)acc[r] + bias[n];
  }
}

__global__ __launch_bounds__(256,2) void mlp_kernel(
    const float* __restrict__ rays, const float* __restrict__ zbuf,
    const float* __restrict__ scaleb, const _Float16* __restrict__ wt,
    const float* __restrict__ bias, float* __restrict__ sigmaws,
    float* __restrict__ rgbws, _Float16* __restrict__ semws)
{
  extern __shared__ uint8_t smem[];
  const int p0 = blockIdx.x*64;
  const int t = threadIdx.x;
  const int m = t & 63, g = t >> 6;
  const int p = p0 + m;
  const int ray = p / SAMP;
  const float sc = scaleb[ray];
  const float z  = zbuf[p];
  const float ox = rays[ray*6+0], oy = rays[ray*6+1], oz = rays[ray*6+2];
  const float dx = rays[ray*6+3], dy = rays[ray*6+4], dz = rays[ray*6+5];
  const float x0 = (ox + dx*z/sc)/200.f;
  const float x1 = (oy + dy*z/sc)/200.f;
  const float x2 = (oz + dz*z/sc)/200.f;
  const float u0 = dx/sc, u1 = dy/sc, u2 = dz/sc;
  // x_enc -> bufX: each thread row m, cols g*16..g*16+15 (two 16B writes)
  {
    union { _Float16 hv[8]; half8 v; } u8;
#pragma unroll
    for (int half = 0; half < 2; ++half) {
      const int j0 = g*16 + half*8;
#pragma unroll
      for (int jj = 0; jj < 8; ++jj) u8.hv[jj] = (_Float16)xenc_val(j0+jj, x0, x1, x2);
      *(half8*)(smem + laddrX(m, j0)) = u8.v;
    }
  }
  __syncthreads();
  gemm<2 ,8,2,0,true ,0     >(smem, LDS_X, LDS_A, wt+WT0_OFF,         0,  bias+0,    p0, sigmaws, semws); __syncthreads();
  gemm<8 ,8,2,0,true ,100000>(smem, LDS_A, LDS_B, wt+WTH_OFF+0*65536, 0,  bias+256,  p0, sigmaws, semws); __syncthreads();
  gemm<8 ,8,2,0,true ,100000>(smem, LDS_B, LDS_A, wt+WTH_OFF+1*65536, 0,  bias+512,  p0, sigmaws, semws); __syncthreads();
  gemm<8 ,8,2,0,true ,100000>(smem, LDS_A, LDS_B, wt+WTH_OFF+2*65536, 0,  bias+768,  p0, sigmaws, semws); __syncthreads();
  gemm<10,8,2,0,true ,256   >(smem, LDS_B, LDS_A, wt+WTS_OFF,         0,  bias+1024, p0, sigmaws, semws); __syncthreads();
  // overwrite bufX cols 0..31 with d_enc (x_enc dead after skip layer)
  if (g < 4) {
    union { _Float16 hv[8]; half8 v; } u8;
    const int c0 = g*8;
#pragma unroll
    for (int cc = 0; cc < 8; ++cc) u8.hv[cc] = (_Float16)denc_val(c0+cc, u0, u1, u2);
    *(half8*)(smem + laddrX(m, c0)) = u8.v;
  }
  gemm<8 ,8,2,0,true ,100000>(smem, LDS_A, LDS_B, wt+WTH_OFF+3*65536, 0,  bias+1280, p0, sigmaws, semws); __syncthreads();
  gemm<8 ,8,2,0,true ,100000>(smem, LDS_B, LDS_A, wt+WTH_OFF+4*65536, 0,  bias+1536, p0, sigmaws, semws); __syncthreads();
  gemm<8 ,8,2,0,true ,100000>(smem, LDS_A, LDS_B, wt+WTH_OFF+5*65536, 0,  bias+1792, p0, sigmaws, semws); __syncthreads();
  // head: feat (cols 0..255) -> bufA ; tail (cols 256..319) -> sem/sigma
  gemm<8 ,8,2,0,false,100000>(smem, LDS_B, LDS_A, wt+WTHD_OFF,        0,  bias+2048, p0, sigmaws, semws);
  gemm<8 ,2,2,1,false,100000>(smem, LDS_B, LDS_A, wt+WTHD_OFF,        16, bias+2304, p0, sigmaws, semws); __syncthreads();
  gemm<9 ,4,2,0,true ,256   >(smem, LDS_A, LDS_B, wt+WTR1_OFF,        0,  bias+2368, p0, sigmaws, semws); __syncthreads();
  gemm_rgb2(smem, LDS_B, wt+WTR2_OFF, bias+2496, p0, rgbws);
}

// ============================================================== compositing
__global__ __launch_bounds__(128) void comp_kernel(
    const float* __restrict__ inter, const float* __restrict__ zbuf,
    const float* __restrict__ scaleb, const float* __restrict__ sigmaws,
    const float* __restrict__ rgbws, const _Float16* __restrict__ semws,
    float* __restrict__ out)
{
  __shared__ float zt[84], alpha[84], wgt[84];
  const int ray = blockIdx.x, t = threadIdx.x;
  const float sc = scaleb[ray];
  const float* bx = inter + (size_t)ray*40;
  if (t < 84) zt[t] = zbuf[(size_t)ray*84 + t] / sc;
  __syncthreads();
  if (t < 84) {
    const float z = zbuf[(size_t)ray*84 + t];
    bool inside = false, bound = false;
    for (int b = 0; b < 10; ++b) {
      const float nr = bx[b*4], fr = bx[b*4+1];
      inside = inside || (z > nr && z < fr);
      const float d1 = z - fr, d2 = nr - z;
      bound = bound || (d1 > 0.f && d1 < 1e-3f) || (d2 > 0.f && d2 < 1e-3f);
    }
    float sg = sigmaws[(size_t)ray*84 + t];
    const bool bbox = (z < 200.f) && !inside;
    if (bbox || bound) sg = 0.f;
    sg = fmaxf(sg, 0.f);
    const float dist = (t < 83) ? (zt[t+1] - zt[t])*sc : 1e10f*sc;
    alpha[t] = 1.f - expf(-sg*dist);
  }
  __syncthreads();
  if (t == 0) {
    float T = 1.f;
    for (int s = 0; s < 84; ++s) { wgt[s] = alpha[s]*T; T *= (1.f - alpha[s] + 1e-10f); }
  }
  __syncthreads();
  if (t < 55) {
    float a = 0.f;
    const size_t base = (size_t)ray*84;
    if (t < 50) {
      for (int s = 0; s < 84; ++s) a += wgt[s]*(float)semws[(base+s)*SEMSTR + t];
      out[(size_t)ray*55 + 5 + t] = a;
    } else if (t < 53) {
      const int c = t - 50;
      for (int s = 0; s < 84; ++s) { const float r = rgbws[(base+s)*3 + c]; a += wgt[s]/(1.f + expf(-r)); }
      out[(size_t)ray*55 + c] = a;
    } else if (t == 53) {
      for (int s = 0; s < 84; ++s) a += wgt[s]*zt[s];
      out[(size_t)ray*55 + 3] = a;
    } else {
      for (int s = 0; s < 84; ++s) a += wgt[s];
      out[(size_t)ray*55 + 4] = a;
    }
  }
}

// ============================================================== launch
extern "C" void kernel_launch(void* const* d_in, const int* in_sizes, int n_in,
                              void* d_out, int out_size, void* d_ws, size_t ws_size,
                              hipStream_t stream) {
  const float* rays   = (const float*)d_in[0];
  const float* inter  = (const float*)d_in[1];
  const float* noise  = (const float*)d_in[2];
  const float* w_in   = (const float*)d_in[3];
  const float* b_in   = (const float*)d_in[4];
  const float* w_h    = (const float*)d_in[5];
  const float* b_h    = (const float*)d_in[6];
  const float* w_skip = (const float*)d_in[7];
  const float* b_skip = (const float*)d_in[8];
  const float* w_sig  = (const float*)d_in[9];
  const float* b_sig  = (const float*)d_in[10];
  const float* w_feat = (const float*)d_in[11];
  const float* b_feat = (const float*)d_in[12];
  const float* w_rgb1 = (const float*)d_in[13];
  const float* b_rgb1 = (const float*)d_in[14];
  const float* w_rgb2 = (const float*)d_in[15];
  const float* b_rgb2 = (const float*)d_in[16];
  const float* w_sem  = (const float*)d_in[17];
  const float* b_sem  = (const float*)d_in[18];

  uint8_t* ws = (uint8_t*)d_ws;
  _Float16* wt    = (_Float16*)(ws + OFF_WT);
  float* bias     = (float*)(ws + OFF_BIAS);
  float* zbuf     = (float*)(ws + OFF_Z);
  float* scaleb   = (float*)(ws + OFF_SCALE);
  float* sigmaws  = (float*)(ws + OFF_SIGMA);
  float* rgbws    = (float*)(ws + OFF_RGB);
  _Float16* semws = (_Float16*)(ws + OFF_SEM);

  prep_kernel<<<dim3((WT_TOTAL + NBIAS + 255)/256), dim3(256), 0, stream>>>(
      w_in, w_h, w_skip, w_sig, w_feat, w_rgb1, w_rgb2, w_sem,
      b_in, b_h, b_skip, b_sig, b_feat, b_rgb1, b_rgb2, b_sem, wt, bias);
  sample_kernel<<<dim3(NRAYS), dim3(256), 0, stream>>>(rays, inter, noise, zbuf, scaleb);
  mlp_kernel<<<dim3(NPTS/64), dim3(256), LDS_TOTAL, stream>>>(
      rays, zbuf, scaleb, wt, bias, sigmaws, rgbws, semws);
  comp_kernel<<<dim3(NRAYS), dim3(128), 0, stream>>>(
      inter, zbuf, scaleb, sigmaws, rgbws, semws, (float*)d_out);
}

// Round 6
// 272.535 us; speedup vs baseline: 1.3349x; 1.1815x over previous
//
#include <hip/hip_runtime.h>

typedef _Float16 half8 __attribute__((ext_vector_type(8)));
typedef float f32x4 __attribute__((ext_vector_type(4)));

#define NRAYS 2048
#define SAMP 84
#define NPTS (NRAYS*SAMP)   // 172032
#define SEMSTR 52           // padded sem row stride (halves)

// ---- half-element offsets inside the weight region (fragment-packed) ----
// layout per region: [frag F][kt][lane l][h 0..7] ; n = F*16 + (l&15), k = kt*32 + (l>>4)*8 + h
#define WT0_OFF   0         // 16 frags x KT2
#define WTH_OFF   16384     // 6 x (16 frags x KT8)
#define WTS_OFF   409600    // 16 frags x KT10
#define WTHD_OFF  491520    // 20 frags x KT8
#define WTR1_OFF  573440    // 8 frags x KT9
#define WTR2_OFF  610304    // 1 frag x KT4
#define WT_TOTAL  612352
#define NBIAS     2512

// ---- ws byte offsets ----
#define OFF_WT    ((size_t)0)
#define OFF_BIAS  ((size_t)1224704)                 // WT_TOTAL*2
#define OFF_Z     (OFF_BIAS + (size_t)NBIAS*4)
#define OFF_SCALE (OFF_Z + (size_t)NPTS*4)
#define OFF_SIGMA (OFF_SCALE + (size_t)NRAYS*4)
#define OFF_RGB   (OFF_SIGMA + (size_t)NPTS*4)
#define OFF_SEM   (OFF_RGB + (size_t)NPTS*12)

// ============================================================== prep
__global__ __launch_bounds__(256) void prep_kernel(
    const float* __restrict__ w_in,  const float* __restrict__ w_h,
    const float* __restrict__ w_skip,const float* __restrict__ w_sigma,
    const float* __restrict__ w_feat,const float* __restrict__ w_rgb1,
    const float* __restrict__ w_rgb2,const float* __restrict__ w_sem,
    const float* __restrict__ b_in,  const float* __restrict__ b_h,
    const float* __restrict__ b_skip,const float* __restrict__ b_sigma,
    const float* __restrict__ b_feat,const float* __restrict__ b_rgb1,
    const float* __restrict__ b_rgb2,const float* __restrict__ b_sem,
    _Float16* __restrict__ wt, float* __restrict__ bias)
{
  int idx = blockIdx.x*256 + threadIdx.x;
  if (idx < WT_TOTAL) {
    float v; int n, k, l, h, q;
    if (idx < WTH_OFF) {                 // L0: 16 frags, KT=2
      int r = idx; int F = r >> 10; int rem = r & 1023; int kt = rem >> 9; q = rem & 511;
      l = q >> 3; h = q & 7;
      n = F*16 + (l&15); k = kt*32 + (l>>4)*8 + h;
      v = (k < 63) ? w_in[k*256 + n] : 0.f;
    } else if (idx < WTS_OFF) {          // hidden: 6 x (16 frags x KT8)
      int r = idx - WTH_OFF; int i = r >> 16; int r2 = r & 65535;
      int F = r2 >> 12; int kt = (r2 >> 9) & 7; q = r2 & 511;
      l = q >> 3; h = q & 7;
      n = F*16 + (l&15); k = kt*32 + (l>>4)*8 + h;
      v = w_h[(i<<16) + (k<<8) + n];
    } else if (idx < WTHD_OFF) {         // skip: 16 frags x KT10
      int r = idx - WTS_OFF; int F = r / 5120; int rem = r % 5120; int kt = rem >> 9; q = rem & 511;
      l = q >> 3; h = q & 7;
      n = F*16 + (l&15); k = kt*32 + (l>>4)*8 + h;
      v = (k < 319) ? w_skip[k*256 + n] : 0.f;
    } else if (idx < WTR1_OFF) {         // head: 20 frags x KT8
      int r = idx - WTHD_OFF; int F = r >> 12; int kt = (r >> 9) & 7; q = r & 511;
      l = q >> 3; h = q & 7;
      n = F*16 + (l&15); k = kt*32 + (l>>4)*8 + h;
      v = (n < 256) ? w_feat[(k<<8) + n]
        : (n < 306) ? w_sem[k*50 + (n-256)]
        : (n == 306)? w_sigma[k] : 0.f;
    } else if (idx < WTR2_OFF) {         // rgb1: 8 frags x KT9
      int r = idx - WTR1_OFF; int F = r / 4608; int rem = r % 4608; int kt = rem >> 9; q = rem & 511;
      l = q >> 3; h = q & 7;
      n = F*16 + (l&15); k = kt*32 + (l>>4)*8 + h;
      v = (k < 283) ? w_rgb1[k*128 + n] : 0.f;
    } else {                             // rgb2: 1 frag x KT4
      int r = idx - WTR2_OFF; int kt = r >> 9; q = r & 511;
      l = q >> 3; h = q & 7;
      n = (l&15); k = kt*32 + (l>>4)*8 + h;
      v = (n < 3) ? w_rgb2[k*3 + n] : 0.f;
    }
    wt[idx] = (_Float16)v;
  } else if (idx < WT_TOTAL + NBIAS) {
    int j = idx - WT_TOTAL; float v;
    if (j < 2048) {
      int i = j >> 8, c = j & 255;
      v = (i==0) ? b_in[c] : (i<4) ? b_h[(i-1)*256+c]
        : (i==4) ? b_skip[c] : b_h[(i-2)*256+c];
    } else if (j < 2368) {
      int c = j - 2048;
      v = (c<256) ? b_feat[c] : (c<306) ? b_sem[c-256]
        : (c==306) ? b_sigma[0] : 0.f;
    } else if (j < 2496) v = b_rgb1[j-2368];
    else { int c = j-2496; v = (c<3) ? b_rgb2[c] : 0.f; }
    bias[j] = v;
  }
}

// ============================================================== sampling
__global__ __launch_bounds__(256) void sample_kernel(
    const float* __restrict__ rays, const float* __restrict__ inter,
    const float* __restrict__ noise, float* __restrict__ zbuf,
    float* __restrict__ scaleb)
{
  __shared__ float sv[240], ss[240], z2[84];
  const int ray = blockIdx.x, t = threadIdx.x;
  const float* bx = inter + (size_t)ray*40;
  if (t < 240) {
    int b = t/24, j = t%24;
    float nr = bx[b*4], fr = bx[b*4+1];
    float tj = (j==23) ? 1.f : (float)j * (1.f/23.f);
    sv[t] = nr + (fr-nr)*tj;
  }
  __syncthreads();
  if (t < 240) {
    float v = sv[t]; int r = 0;
    for (int i = 0; i < 240; ++i) { float vi = sv[i]; r += (vi < v) || (vi == v && i < t); }
    ss[r] = v;
  }
  __syncthreads();
  if (t < 64) {
    float z;
    if (t == 63) z = ss[239];
    else { int num = t*239; int k = num/63; float f = (float)(num - k*63)*(1.f/63.f);
           z = ss[k] + f*(ss[k+1]-ss[k]); }
    z2[t] = z;
  } else if (t < 84) {
    int b = t - 64;
    z2[t] = (b < 10) ? (bx[b*4] - 1e-5f) : (bx[(b-10)*4+1] + 1e-5f);
  }
  __syncthreads();
  if (t < 84) { float z = z2[t]; if (z < 0.f) z = 200.f + 20.f*noise[(size_t)ray*84 + t]; z2[t] = z; }
  __syncthreads();
  if (t < 84) {
    float v = z2[t]; int r = 0;
    for (int i = 0; i < 84; ++i) { float vi = z2[i]; r += (vi < v) || (vi == v && i < t); }
    zbuf[(size_t)ray*84 + r] = v;
  }
  if (t == 0) {
    float dx = rays[ray*6+3], dy = rays[ray*6+4], dz = rays[ray*6+5];
    scaleb[ray] = sqrtf(dx*dx + dy*dy + dz*dz);
  }
}

// ============================================================== MLP
// 64 points/block, 256 threads (4 waves, pure n-split). Per wave: ALL 64 rows x NF*16 cols.
// LDS: bufA (64x256 f16, 32KB) @0, bufB @32768, bufX (64x64 f16, 8KB) @65536. 72KB -> 2 blocks/CU.
#define LDS_A 0u
#define LDS_B 32768u
#define LDS_X 65536u
#define LDS_TOTAL 73728

__device__ __forceinline__ uint32_t laddr(uint32_t base, int m, int k) {
  return base + (uint32_t)(m*512) + (uint32_t)((((k>>3)^(m&7))<<4) + ((k&7)<<1));
}
__device__ __forceinline__ uint32_t laddrX(int m, int k) {
  return LDS_X + (uint32_t)(m*128) + (uint32_t)(((((k>>3)&7)^(m&7))<<4) + ((k&7)<<1));
}
struct __attribute__((aligned(8))) H4 { _Float16 h[4]; };

__device__ __forceinline__ float xenc_val(int j, float x0, float x1, float x2) {
  if (j >= 63) return 0.f;
  if (j < 3) return j==0?x0:(j==1?x1:x2);
  int q = j-3, lf = q/6, r = q%6, ci = r%3;
  float xc = (ci==0)?x0:((ci==1)?x1:x2);
  float arg = xc * (float)(1<<lf);
  return (r<3) ? sinf(arg) : cosf(arg);
}
__device__ __forceinline__ float denc_val(int c, float u0, float u1, float u2) {
  if (c >= 27) return 0.f;
  if (c < 3) return c==0?u0:(c==1?u1:u2);
  int q = c-3, lf = q/6, r = q%6, ci = r%3;
  float uc = (ci==0)?u0:((ci==1)?u1:u2);
  float arg = uc * (float)(1<<lf);
  return (r<3) ? sinf(arg) : cosf(arg);
}

// 4 waves, wave w = n-slice: frags [w*NF, w*NF+NF), rows 0..63 (MF=4).
// Weight ring: depth DW, refill lead LEAD=DW-1 (LEAD % DW != 0 so refill slot
// (kt+LEAD)%DW never collides with consume slot kt%DW in the same iteration).
// Prologue loads slots 0..LEAD-1; refill for kt+LEAD issued BEFORE the MFMA
// cluster of iteration kt, pinned by sched_barrier(0).
// XSTART: 0 => input entirely bufX; 100000 => entirely inb; else k>=XSTART reads bufX col k-XSTART.
// MODE 0: write smem outb (opt RELU). MODE 1: head — n0<256 -> feat to outb, else sem/sigma.
template<int KT, int NF, int MODE, bool RELU, int XSTART>
__device__ __forceinline__ void gemm(uint8_t* smem, uint32_t inb, uint32_t outb,
    const _Float16* __restrict__ WT, int fbase, const float* __restrict__ biasptr,
    int p0, float* __restrict__ sigmaws, _Float16* __restrict__ semws)
{
  constexpr int MF = 4;
  const int t = threadIdx.x;
  const int l = t & 63, w = t >> 6;
  const int lr = l & 15, lg = l >> 4;
  const int wn = w & 3;
  constexpr int DW   = (KT <= 3) ? KT : ((NF > 4) ? 3 : 4);
  constexpr int LEAD = (KT <= 3) ? KT : DW - 1;
  f32x4 acc[NF][MF];
#pragma unroll
  for (int i = 0; i < NF; ++i)
#pragma unroll
    for (int j = 0; j < MF; ++j) acc[i][j] = (f32x4){0.f,0.f,0.f,0.f};
  const _Float16* wb = WT + (size_t)((fbase + wn*NF)*KT)*512 + (size_t)l*8;
  half8 av[DW][NF];
  half8 bv[2][MF];
  auto baddr = [&](int row, int kt)->uint32_t {
    const int kk = kt*32 + lg*8;
    if (XSTART == 0) return laddrX(row, kk);
    if (XSTART < 100000 && kt*32 >= XSTART) return laddrX(row, kk - XSTART);
    return laddr(inb, row, kk);
  };
  // prologue: weights kt=0..LEAD-1 into slots 0..LEAD-1, activations kt=0
#pragma unroll
  for (int d = 0; d < LEAD && d < KT; ++d)
#pragma unroll
    for (int nf = 0; nf < NF; ++nf)
      av[d][nf] = *(const half8*)(wb + (size_t)(nf*KT + d)*512);
#pragma unroll
  for (int mf = 0; mf < MF; ++mf)
    bv[0][mf] = *(const half8*)(smem + baddr(mf*16 + lr, 0));
#pragma unroll
  for (int kt = 0; kt < KT; ++kt) {
    // issue future loads BEFORE the MFMA cluster, then pin.
    if (kt + 1 < KT) {
#pragma unroll
      for (int mf = 0; mf < MF; ++mf)
        bv[(kt+1)&1][mf] = *(const half8*)(smem + baddr(mf*16 + lr, kt+1));
    }
    if (kt + LEAD < KT) {
#pragma unroll
      for (int nf = 0; nf < NF; ++nf)
        av[(kt+LEAD)%DW][nf] = *(const half8*)(wb + (size_t)(nf*KT + kt + LEAD)*512);
    }
    __builtin_amdgcn_sched_barrier(0);
#pragma unroll
    for (int nf = 0; nf < NF; ++nf)
#pragma unroll
      for (int mf = 0; mf < MF; ++mf)
        acc[nf][mf] = __builtin_amdgcn_mfma_f32_16x16x32_f16(av[kt%DW][nf], bv[kt&1][mf], acc[nf][mf], 0, 0, 0);
    __builtin_amdgcn_sched_barrier(0);
  }
#pragma unroll
  for (int nf = 0; nf < NF; ++nf) {
    const int n0 = (wn*NF + nf)*16;
    const int nb = n0 + lg*4;
    const f32x4 bvv = *(const f32x4*)(biasptr + nb);
    if (MODE == 0 || n0 < 256) {
#pragma unroll
      for (int mf = 0; mf < MF; ++mf) {
        const int m = mf*16 + lr;
        f32x4 v = acc[nf][mf] + bvv;
        H4 hh;
#pragma unroll
        for (int r = 0; r < 4; ++r) { float x = v[r]; if (RELU) x = fmaxf(x, 0.f); hh.h[r] = (_Float16)x; }
        *(H4*)(smem + laddr(outb, m, nb)) = hh;
      }
    } else {
      const int cb = nb - 256;                  // sem/sigma col offset (0..63)
#pragma unroll
      for (int mf = 0; mf < MF; ++mf) {
        const int m = mf*16 + lr;
        const int pp = p0 + m;
        f32x4 v = acc[nf][mf] + bvv;
        if (cb <= 44) {                         // 4 sem cols, 8B-aligned store
          H4 hh;
#pragma unroll
          for (int r = 0; r < 4; ++r) hh.h[r] = (_Float16)v[r];
          *(H4*)(semws + (size_t)pp*SEMSTR + cb) = hh;
        } else if (cb == 48) {                  // sem 48,49 + sigma (n=306)
          semws[(size_t)pp*SEMSTR + 48] = (_Float16)v[0];
          semws[(size_t)pp*SEMSTR + 49] = (_Float16)v[1];
          sigmaws[pp] = v[2];
        }
      }
    }
  }
}

__device__ __forceinline__ void gemm_rgb2(uint8_t* smem, uint32_t inb,
    const _Float16* __restrict__ WT, const float* __restrict__ bias,
    int p0, float* __restrict__ rgbws)
{
  const int t = threadIdx.x;
  const int l = t & 63, w = t >> 6;
  const int lr = l & 15, lg = l >> 4;
  const int m0 = w*16;
  f32x4 acc = (f32x4){0.f,0.f,0.f,0.f};
#pragma unroll
  for (int kt = 0; kt < 4; ++kt) {
    const int kk = kt*32 + lg*8;
    half8 a = *(const half8*)(WT + (size_t)kt*512 + (size_t)l*8);
    half8 b = *(const half8*)(smem + laddr(inb, m0 + lr, kk));
    acc = __builtin_amdgcn_mfma_f32_16x16x32_f16(a, b, acc, 0, 0, 0);
  }
  const int pp = p0 + m0 + lr;
#pragma unroll
  for (int r = 0; r < 4; ++r) {
    const int n = lg*4 + r;
    if (n < 3) rgbws[(size_t)pp*3 + n] = (float)acc[r] + bias[n];
  }
}

__global__ __launch_bounds__(256,2) void mlp_kernel(
    const float* __restrict__ rays, const float* __restrict__ zbuf,
    const float* __restrict__ scaleb, const _Float16* __restrict__ wt,
    const float* __restrict__ bias, float* __restrict__ sigmaws,
    float* __restrict__ rgbws, _Float16* __restrict__ semws)
{
  extern __shared__ uint8_t smem[];
  const int p0 = blockIdx.x*64;
  const int t = threadIdx.x;
  const int m = t & 63, g = t >> 6;
  const int p = p0 + m;
  const int ray = p / SAMP;
  const float sc = scaleb[ray];
  const float z  = zbuf[p];
  const float ox = rays[ray*6+0], oy = rays[ray*6+1], oz = rays[ray*6+2];
  const float dx = rays[ray*6+3], dy = rays[ray*6+4], dz = rays[ray*6+5];
  const float x0 = (ox + dx*z/sc)/200.f;
  const float x1 = (oy + dy*z/sc)/200.f;
  const float x2 = (oz + dz*z/sc)/200.f;
  const float u0 = dx/sc, u1 = dy/sc, u2 = dz/sc;
  // x_enc -> bufX: each thread row m, cols g*16..g*16+15 (two 16B writes)
  {
    union { _Float16 hv[8]; half8 v; } u8;
#pragma unroll
    for (int hf = 0; hf < 2; ++hf) {
      const int j0 = g*16 + hf*8;
#pragma unroll
      for (int jj = 0; jj < 8; ++jj) u8.hv[jj] = (_Float16)xenc_val(j0+jj, x0, x1, x2);
      *(half8*)(smem + laddrX(m, j0)) = u8.v;
    }
  }
  __syncthreads();
  gemm<2 ,4,0,true ,0     >(smem, LDS_X, LDS_A, wt+WT0_OFF,         0, bias+0,    p0, sigmaws, semws); __syncthreads();
  gemm<8 ,4,0,true ,100000>(smem, LDS_A, LDS_B, wt+WTH_OFF+0*65536, 0, bias+256,  p0, sigmaws, semws); __syncthreads();
  gemm<8 ,4,0,true ,100000>(smem, LDS_B, LDS_A, wt+WTH_OFF+1*65536, 0, bias+512,  p0, sigmaws, semws); __syncthreads();
  gemm<8 ,4,0,true ,100000>(smem, LDS_A, LDS_B, wt+WTH_OFF+2*65536, 0, bias+768,  p0, sigmaws, semws); __syncthreads();
  gemm<10,4,0,true ,256   >(smem, LDS_B, LDS_A, wt+WTS_OFF,         0, bias+1024, p0, sigmaws, semws); __syncthreads();
  // overwrite bufX cols 0..31 with d_enc (x_enc dead after skip layer)
  {
    union { _Float16 hv[8]; half8 v; } u8;
    const int c0 = g*8;
#pragma unroll
    for (int cc = 0; cc < 8; ++cc) u8.hv[cc] = (_Float16)denc_val(c0+cc, u0, u1, u2);
    *(half8*)(smem + laddrX(m, c0)) = u8.v;
  }
  gemm<8 ,4,0,true ,100000>(smem, LDS_A, LDS_B, wt+WTH_OFF+3*65536, 0, bias+1280, p0, sigmaws, semws); __syncthreads();
  gemm<8 ,4,0,true ,100000>(smem, LDS_B, LDS_A, wt+WTH_OFF+4*65536, 0, bias+1536, p0, sigmaws, semws); __syncthreads();
  gemm<8 ,4,0,true ,100000>(smem, LDS_A, LDS_B, wt+WTH_OFF+5*65536, 0, bias+1792, p0, sigmaws, semws); __syncthreads();
  // head: 320 cols in one pass (feat -> bufA, sem/sigma -> ws)
  gemm<8 ,5,1,false,100000>(smem, LDS_B, LDS_A, wt+WTHD_OFF,        0, bias+2048, p0, sigmaws, semws); __syncthreads();
  gemm<9 ,2,0,true ,256   >(smem, LDS_A, LDS_B, wt+WTR1_OFF,        0, bias+2368, p0, sigmaws, semws); __syncthreads();
  gemm_rgb2(smem, LDS_B, wt+WTR2_OFF, bias+2496, p0, rgbws);
}

// ============================================================== compositing
__global__ __launch_bounds__(128) void comp_kernel(
    const float* __restrict__ inter, const float* __restrict__ zbuf,
    const float* __restrict__ scaleb, const float* __restrict__ sigmaws,
    const float* __restrict__ rgbws, const _Float16* __restrict__ semws,
    float* __restrict__ out)
{
  __shared__ float zt[84], alpha[84], wgt[84];
  const int ray = blockIdx.x, t = threadIdx.x;
  const float sc = scaleb[ray];
  const float* bx = inter + (size_t)ray*40;
  if (t < 84) zt[t] = zbuf[(size_t)ray*84 + t] / sc;
  __syncthreads();
  if (t < 84) {
    const float z = zbuf[(size_t)ray*84 + t];
    bool inside = false, bound = false;
    for (int b = 0; b < 10; ++b) {
      const float nr = bx[b*4], fr = bx[b*4+1];
      inside = inside || (z > nr && z < fr);
      const float d1 = z - fr, d2 = nr - z;
      bound = bound || (d1 > 0.f && d1 < 1e-3f) || (d2 > 0.f && d2 < 1e-3f);
    }
    float sg = sigmaws[(size_t)ray*84 + t];
    const bool bbox = (z < 200.f) && !inside;
    if (bbox || bound) sg = 0.f;
    sg = fmaxf(sg, 0.f);
    const float dist = (t < 83) ? (zt[t+1] - zt[t])*sc : 1e10f*sc;
    alpha[t] = 1.f - expf(-sg*dist);
  }
  __syncthreads();
  if (t == 0) {
    float T = 1.f;
    for (int s = 0; s < 84; ++s) { wgt[s] = alpha[s]*T; T *= (1.f - alpha[s] + 1e-10f); }
  }
  __syncthreads();
  if (t < 55) {
    float a = 0.f;
    const size_t base = (size_t)ray*84;
    if (t < 50) {
      for (int s = 0; s < 84; ++s) a += wgt[s]*(float)semws[(base+s)*SEMSTR + t];
      out[(size_t)ray*55 + 5 + t] = a;
    } else if (t < 53) {
      const int c = t - 50;
      for (int s = 0; s < 84; ++s) { const float r = rgbws[(base+s)*3 + c]; a += wgt[s]/(1.f + expf(-r)); }
      out[(size_t)ray*55 + c] = a;
    } else if (t == 53) {
      for (int s = 0; s < 84; ++s) a += wgt[s]*zt[s];
      out[(size_t)ray*55 + 3] = a;
    } else {
      for (int s = 0; s < 84; ++s) a += wgt[s];
      out[(size_t)ray*55 + 4] = a;
    }
  }
}

// ============================================================== launch
extern "C" void kernel_launch(void* const* d_in, const int* in_sizes, int n_in,
                              void* d_out, int out_size, void* d_ws, size_t ws_size,
                              hipStream_t stream) {
  const float* rays   = (const float*)d_in[0];
  const float* inter  = (const float*)d_in[1];
  const float* noise  = (const float*)d_in[2];
  const float* w_in   = (const float*)d_in[3];
  const float* b_in   = (const float*)d_in[4];
  const float* w_h    = (const float*)d_in[5];
  const float* b_h    = (const float*)d_in[6];
  const float* w_skip = (const float*)d_in[7];
  const float* b_skip = (const float*)d_in[8];
  const float* w_sig  = (const float*)d_in[9];
  const float* b_sig  = (const float*)d_in[10];
  const float* w_feat = (const float*)d_in[11];
  const float* b_feat = (const float*)d_in[12];
  const float* w_rgb1 = (const float*)d_in[13];
  const float* b_rgb1 = (const float*)d_in[14];
  const float* w_rgb2 = (const float*)d_in[15];
  const float* b_rgb2 = (const float*)d_in[16];
  const float* w_sem  = (const float*)d_in[17];
  const float* b_sem  = (const float*)d_in[18];

  uint8_t* ws = (uint8_t*)d_ws;
  _Float16* wt    = (_Float16*)(ws + OFF_WT);
  float* bias     = (float*)(ws + OFF_BIAS);
  float* zbuf     = (float*)(ws + OFF_Z);
  float* scaleb   = (float*)(ws + OFF_SCALE);
  float* sigmaws  = (float*)(ws + OFF_SIGMA);
  float* rgbws    = (float*)(ws + OFF_RGB);
  _Float16* semws = (_Float16*)(ws + OFF_SEM);

  prep_kernel<<<dim3((WT_TOTAL + NBIAS + 255)/256), dim3(256), 0, stream>>>(
      w_in, w_h, w_skip, w_sig, w_feat, w_rgb1, w_rgb2, w_sem,
      b_in, b_h, b_skip, b_sig, b_feat, b_rgb1, b_rgb2, b_sem, wt, bias);
  sample_kernel<<<dim3(NRAYS), dim3(256), 0, stream>>>(rays, inter, noise, zbuf, scaleb);
  mlp_kernel<<<dim3(NPTS/64), dim3(256), LDS_TOTAL, stream>>>(
      rays, zbuf, scaleb, wt, bias, sigmaws, rgbws, semws);
  comp_kernel<<<dim3(NRAYS), dim3(128), 0, stream>>>(
      inter, zbuf, scaleb, sigmaws, rgbws, semws, (float*)d_out);
}